// Round 6
// baseline (91.715 us; speedup 1.0000x reference)
//
#include <hip/hip_runtime.h>

#define B_    8
#define OXD   30
#define OYD   30
#define OZD   14
#define NLOC  (OXD*OYD*OZD)      // 12600
#define F_    16
#define T_    216                // 3*3*3*8
#define WPL   (T_*F_)            // 3456 weights per location
#define WPL4  (WPL/4)            // 864 float4
#define NQ    5                  // locations per block
#define NBLK  (NLOC/NQ)          // 2520

// (128, 2): min 2 waves/EU -> VGPR cap 256. Without this hipcc targeted 8
// waves/EU, clamped to 64 VGPRs, and spilled the whole software pipeline
// (R5: WRITE_SIZE 161 MB of scratch, 116 us).
__global__ __launch_bounds__(128, 2)
void lc3d_kernel(const float* __restrict__ in, const float* __restrict__ wgt,
                 const float* __restrict__ bias, float* __restrict__ out) {
    __shared__ float patch[B_ * T_];   // 6.9 KB, rewritten for each location
    __shared__ float red[2][2 * 128];  // double-buffered cross-wave partials, 2 KB
    float4* patch4 = reinterpret_cast<float4*>(patch);
    const float4* in4  = reinterpret_cast<const float4*>(in);
    const float4* wgt4 = reinterpret_cast<const float4*>(wgt);

    const int tid  = threadIdx.x;
    const int fq   = tid & 3;          // f quadrant
    const int tg   = tid >> 2;         // 0..31 t-group
    const int loc0 = blockIdx.x * NQ;

    // ---- per-thread patch-load bases, location-independent part.
    int base4[4];
    #pragma unroll
    for (int r = 0; r < 4; ++r) {
        int idx = tid + 128 * r;
        int seg = idx / 6;             // b*9 + ij
        int off = idx - seg * 6;
        int b   = seg / 9;
        int ij  = seg - b * 9;
        int i   = ij / 3;
        int j   = ij - i * 3;
        base4[r] = (((b * 32 + i) * 32 + j) * 16) * 2 + off;
    }

    // ---- prologue: issue loc0's weight + patch loads
    float4 w[7], p[4];
    {
        const int loc = loc0;
        const int ox  = loc / (OYD * OZD);
        const int rem = loc - ox * (OYD * OZD);
        const int oy  = rem / OZD;
        const int oz  = rem - oy * OZD;
        const int lo4 = ((ox * 32 + oy) * 16 + oz) * 2;
        const float4* wl = wgt4 + (size_t)loc * WPL4 + tid;
        #pragma unroll
        for (int it = 0; it < 6; ++it) w[it] = wl[it * 128];
        w[6] = make_float4(0.f, 0.f, 0.f, 0.f);
        if (tid < 96) w[6] = wl[6 * 128];          // tg<24
        #pragma unroll
        for (int r = 0; r < 3; ++r) p[r] = in4[base4[r] + lo4];
        if (tid < 48) p[3] = in4[base4[3] + lo4];
    }

    #pragma unroll
    for (int q = 0; q < NQ; ++q) {
        const int loc = loc0 + q;

        // ---- commit prefetched patch regs to LDS
        #pragma unroll
        for (int r = 0; r < 3; ++r) patch4[tid + 128 * r] = p[r];
        if (tid < 48) patch4[tid + 384] = p[3];
        __syncthreads();

        // ---- issue NEXT location's loads; they fly during this compute
        float4 w2[7], p2[4];
        if (q + 1 < NQ) {
            const int nl  = loc + 1;
            const int ox  = nl / (OYD * OZD);
            const int rem = nl - ox * (OYD * OZD);
            const int oy  = rem / OZD;
            const int oz  = rem - oy * OZD;
            const int lo4 = ((ox * 32 + oy) * 16 + oz) * 2;
            const float4* wl = wgt4 + (size_t)nl * WPL4 + tid;
            #pragma unroll
            for (int it = 0; it < 6; ++it) w2[it] = wl[it * 128];
            w2[6] = make_float4(0.f, 0.f, 0.f, 0.f);
            if (tid < 96) w2[6] = wl[6 * 128];
            #pragma unroll
            for (int r = 0; r < 3; ++r) p2[r] = in4[base4[r] + lo4];
            if (tid < 48) p2[3] = in4[base4[3] + lo4];
        }

        const float bi = bias[(size_t)loc * F_ + (tid & 15)];

        // ---- compute (identical to R3's verified loop)
        float a[32];
        #pragma unroll
        for (int e = 0; e < 32; ++e) a[e] = 0.f;

        #pragma unroll
        for (int it = 0; it < 7; ++it) {
            const int t  = tg + 32 * it;
            const int tc = (t < T_) ? t : 0;   // clamp; w[6]=0 there
            const float4 ww = w[it];
            #pragma unroll
            for (int b = 0; b < B_; ++b) {
                const float ps = patch[b * T_ + tc];
                a[b * 4 + 0] += ps * ww.x;
                a[b * 4 + 1] += ps * ww.y;
                a[b * 4 + 2] += ps * ww.z;
                a[b * 4 + 3] += ps * ww.w;
            }
        }

        // ---- in-wave butterfly: 16 t-groups, element-folding (30 shuffles)
#define RSTEP(m, k)                                         \
        {                                                   \
            const bool hi = (tid & (m)) != 0;               \
            _Pragma("unroll")                               \
            for (int e = 0; e < (k); ++e) {                 \
                float v = hi ? a[e] : a[e + (k)];           \
                float r = __shfl_xor(v, (m), 64);           \
                a[e] = (hi ? a[e + (k)] : a[e]) + r;        \
            }                                               \
        }
        RSTEP(4, 16)
        RSTEP(8, 8)
        RSTEP(16, 4)
        RSTEP(32, 2)
#undef RSTEP

        const int eg = ((tid & 4) << 2) | (tid & 8) | ((tid & 16) >> 2) | ((tid & 32) >> 4);
        const int wv = tid >> 6;
        red[q & 1][wv * 128 + (eg + 0) * 4 + fq] = a[0];
        red[q & 1][wv * 128 + (eg + 1) * 4 + fq] = a[1];
        __syncthreads();   // also guarantees all patch reads done before next q

        {
            const int b  = tid >> 4;
            const int f  = tid & 15;
            const int e2 = ((b * 4 + (f & 3)) * 4) + (f >> 2);
            const float s = bi + red[q & 1][e2] + red[q & 1][128 + e2];
            out[((size_t)b * NLOC + loc) * F_ + f] = s;
        }

        // ---- rotate prefetch into current (free: loop is fully unrolled)
        if (q + 1 < NQ) {
            #pragma unroll
            for (int it = 0; it < 7; ++it) w[it] = w2[it];
            #pragma unroll
            for (int r = 0; r < 4; ++r) p[r] = p2[r];
        }
    }
}

extern "C" void kernel_launch(void* const* d_in, const int* in_sizes, int n_in,
                              void* d_out, int out_size, void* d_ws, size_t ws_size,
                              hipStream_t stream) {
    const float* in   = (const float*)d_in[0];
    const float* wgt  = (const float*)d_in[1];
    const float* bias = (const float*)d_in[2];
    float* out = (float*)d_out;
    lc3d_kernel<<<NBLK, 128, 0, stream>>>(in, wgt, bias, out);
}

// Round 7
// 57.124 us; speedup vs baseline: 1.6055x; 1.6055x over previous
//
#include <hip/hip_runtime.h>

#define B_    8
#define OXD   30
#define OYD   30
#define OZD   14
#define NLOC  (OXD*OYD*OZD)      // 12600
#define F_    16
#define T_    216                // 3*3*3*8
#define WPL   (T_*F_)            // 3456 weights per location
#define WPL4  (WPL/4)            // 864 float4
#define NQ    5                  // locations per block
#define NBLK  (NLOC/NQ)          // 2520

// amdgpu_waves_per_eu(2,3): pin the backend's occupancy target. Plain
// __launch_bounds__(128,2) only sets the MIN waves/EU; the heuristic still
// targeted 8 waves/EU -> 64-VGPR clamp -> spilled the software pipeline
// (R5/R6: WRITE_SIZE 162 MB scratch, 116 us). Range max=3 -> >=168 VGPRs.
__global__ __launch_bounds__(128) __attribute__((amdgpu_waves_per_eu(2, 3)))
void lc3d_kernel(const float* __restrict__ in, const float* __restrict__ wgt,
                 const float* __restrict__ bias, float* __restrict__ out) {
    __shared__ float patch[B_ * T_];   // 6.9 KB, rewritten for each location
    __shared__ float red[2][2 * 128];  // double-buffered cross-wave partials, 2 KB
    float4* patch4 = reinterpret_cast<float4*>(patch);
    const float4* in4  = reinterpret_cast<const float4*>(in);
    const float4* wgt4 = reinterpret_cast<const float4*>(wgt);

    const int tid  = threadIdx.x;
    const int fq   = tid & 3;          // f quadrant
    const int tg   = tid >> 2;         // 0..31 t-group
    const int loc0 = blockIdx.x * NQ;

    // ---- per-thread patch-load bases, location-independent part.
    int base4[4];
    #pragma unroll
    for (int r = 0; r < 4; ++r) {
        int idx = tid + 128 * r;
        int seg = idx / 6;             // b*9 + ij
        int off = idx - seg * 6;
        int b   = seg / 9;
        int ij  = seg - b * 9;
        int i   = ij / 3;
        int j   = ij - i * 3;
        base4[r] = (((b * 32 + i) * 32 + j) * 16) * 2 + off;
    }

    // ---- prologue: issue loc0's weight + patch loads
    float4 w[7], p[4];
    {
        const int loc = loc0;
        const int ox  = loc / (OYD * OZD);
        const int rem = loc - ox * (OYD * OZD);
        const int oy  = rem / OZD;
        const int oz  = rem - oy * OZD;
        const int lo4 = ((ox * 32 + oy) * 16 + oz) * 2;
        const float4* wl = wgt4 + (size_t)loc * WPL4 + tid;
        #pragma unroll
        for (int it = 0; it < 6; ++it) w[it] = wl[it * 128];
        w[6] = make_float4(0.f, 0.f, 0.f, 0.f);
        if (tid < 96) w[6] = wl[6 * 128];          // tg<24
        #pragma unroll
        for (int r = 0; r < 3; ++r) p[r] = in4[base4[r] + lo4];
        if (tid < 48) p[3] = in4[base4[3] + lo4];
    }

    #pragma unroll
    for (int q = 0; q < NQ; ++q) {
        const int loc = loc0 + q;

        // ---- commit prefetched patch regs to LDS
        #pragma unroll
        for (int r = 0; r < 3; ++r) patch4[tid + 128 * r] = p[r];
        if (tid < 48) patch4[tid + 384] = p[3];
        __syncthreads();

        // ---- issue NEXT location's loads; they fly during this compute
        float4 w2[7], p2[4];
        if (q + 1 < NQ) {
            const int nl  = loc + 1;
            const int ox  = nl / (OYD * OZD);
            const int rem = nl - ox * (OYD * OZD);
            const int oy  = rem / OZD;
            const int oz  = rem - oy * OZD;
            const int lo4 = ((ox * 32 + oy) * 16 + oz) * 2;
            const float4* wl = wgt4 + (size_t)nl * WPL4 + tid;
            #pragma unroll
            for (int it = 0; it < 6; ++it) w2[it] = wl[it * 128];
            w2[6] = make_float4(0.f, 0.f, 0.f, 0.f);
            if (tid < 96) w2[6] = wl[6 * 128];
            #pragma unroll
            for (int r = 0; r < 3; ++r) p2[r] = in4[base4[r] + lo4];
            if (tid < 48) p2[3] = in4[base4[3] + lo4];
        }

        const float bi = bias[(size_t)loc * F_ + (tid & 15)];

        // ---- compute (identical to R3's verified loop)
        float a[32];
        #pragma unroll
        for (int e = 0; e < 32; ++e) a[e] = 0.f;

        #pragma unroll
        for (int it = 0; it < 7; ++it) {
            const int t  = tg + 32 * it;
            const int tc = (t < T_) ? t : 0;   // clamp; w[6]=0 there
            const float4 ww = w[it];
            #pragma unroll
            for (int b = 0; b < B_; ++b) {
                const float ps = patch[b * T_ + tc];
                a[b * 4 + 0] += ps * ww.x;
                a[b * 4 + 1] += ps * ww.y;
                a[b * 4 + 2] += ps * ww.z;
                a[b * 4 + 3] += ps * ww.w;
            }
        }

        // ---- in-wave butterfly: 16 t-groups, element-folding (30 shuffles)
#define RSTEP(m, k)                                         \
        {                                                   \
            const bool hi = (tid & (m)) != 0;               \
            _Pragma("unroll")                               \
            for (int e = 0; e < (k); ++e) {                 \
                float v = hi ? a[e] : a[e + (k)];           \
                float r = __shfl_xor(v, (m), 64);           \
                a[e] = (hi ? a[e + (k)] : a[e]) + r;        \
            }                                               \
        }
        RSTEP(4, 16)
        RSTEP(8, 8)
        RSTEP(16, 4)
        RSTEP(32, 2)
#undef RSTEP

        const int eg = ((tid & 4) << 2) | (tid & 8) | ((tid & 16) >> 2) | ((tid & 32) >> 4);
        const int wv = tid >> 6;
        red[q & 1][wv * 128 + (eg + 0) * 4 + fq] = a[0];
        red[q & 1][wv * 128 + (eg + 1) * 4 + fq] = a[1];
        __syncthreads();   // also guarantees all patch reads done before next q

        {
            const int b  = tid >> 4;
            const int f  = tid & 15;
            const int e2 = ((b * 4 + (f & 3)) * 4) + (f >> 2);
            const float s = bi + red[q & 1][e2] + red[q & 1][128 + e2];
            out[((size_t)b * NLOC + loc) * F_ + f] = s;
        }

        // ---- rotate prefetch into current (free: loop is fully unrolled)
        if (q + 1 < NQ) {
            #pragma unroll
            for (int it = 0; it < 7; ++it) w[it] = w2[it];
            #pragma unroll
            for (int r = 0; r < 4; ++r) p[r] = p2[r];
        }
    }
}

extern "C" void kernel_launch(void* const* d_in, const int* in_sizes, int n_in,
                              void* d_out, int out_size, void* d_ws, size_t ws_size,
                              hipStream_t stream) {
    const float* in   = (const float*)d_in[0];
    const float* wgt  = (const float*)d_in[1];
    const float* bias = (const float*)d_in[2];
    float* out = (float*)d_out;
    lc3d_kernel<<<NBLK, 128, 0, stream>>>(in, wgt, bias, out);
}

// Round 8
// 36.721 us; speedup vs baseline: 2.4976x; 1.5556x over previous
//
#include <hip/hip_runtime.h>

#define B_   8
#define OXD  30
#define OYD  30
#define OZD  14
#define NLOC (OXD*OYD*OZD)   // 12600
#define CIN  8
#define F_   16
#define T_   216             // 3*3*3*8
#define WPL  (T_*F_)         // 3456 weights per location

// FINAL (reverted R3): weight-stream-bound op. 174 MB of single-use weights
// / 36.6 us = ~5.1 TB/s effective (~80% of 6.3 TB/s achievable). Structural
// attacks tried and nulled: bigger occupancy (R3), shuffle-reduce (R3),
// 2-loc blocks (R4, -6%), register software-pipeline NQ=5 (R7 clean, -56%).
__global__ __launch_bounds__(128)
void lc3d_kernel(const float* __restrict__ in, const float* __restrict__ wgt,
                 const float* __restrict__ bias, float* __restrict__ out) {
    __shared__ float patch[B_ * T_];   // 1728 floats = 6.9 KB
    __shared__ float red[2 * 128];     // 2 waves x 128 partials = 1 KB
    float4* patch4 = reinterpret_cast<float4*>(patch);

    const int loc = blockIdx.x;
    const int ox  = loc / (OYD * OZD);
    const int rem = loc - ox * (OYD * OZD);
    const int oy  = rem / OZD;
    const int oz  = rem - oy * OZD;
    const int tid = threadIdx.x;

    const int fq = tid & 3;            // f quadrant (f = 4*fq .. 4*fq+3)
    const int tg = tid >> 2;           // 0..31 t-group
    const float* wloc = wgt + (size_t)loc * WPL;

    // bias for this thread's eventual output (b,f) = (tid>>4, tid&15)
    const float bi = bias[loc * F_ + (tid & 15)];

    // ---- issue ALL weight loads up front (1 KB contiguous per wave per it)
    float4 w[7];
    #pragma unroll
    for (int it = 0; it < 6; ++it)
        w[it] = *reinterpret_cast<const float4*>(wloc + (tg + 32 * it) * F_ + fq * 4);
    w[6] = make_float4(0.f, 0.f, 0.f, 0.f);
    if (tg < 24)                       // 216 = 6*32 + 24
        w[6] = *reinterpret_cast<const float4*>(wloc + (tg + 192) * F_ + fq * 4);

    // ---- stage input patches as float4 (weight latency hides under this)
    const float4* in4 = reinterpret_cast<const float4*>(in);
    #pragma unroll
    for (int r = 0; r < 4; ++r) {
        int idx = tid + 128 * r;       // 0..431
        if (r < 3 || idx < 432) {
            int seg = idx / 6;         // 0..71 = b*9 + ij
            int off = idx - seg * 6;
            int b   = seg / 9;
            int ij  = seg - b * 9;
            int i   = ij / 3;
            int j   = ij - i * 3;
            int g4  = (((b * 32 + ox + i) * 32 + (oy + j)) * 16 + oz) * 2 + off;
            patch4[idx] = in4[g4];
        }
    }
    __syncthreads();

    // ---- main FMA loop: a[b*4+fi] accumulators
    float a[32];
    #pragma unroll
    for (int e = 0; e < 32; ++e) a[e] = 0.f;

    #pragma unroll
    for (int it = 0; it < 7; ++it) {
        const int t  = tg + 32 * it;
        const int tc = (t < T_) ? t : 0;   // clamp: w[6]=0 there, avoid 0*NaN
        const float4 ww = w[it];
        #pragma unroll
        for (int b = 0; b < B_; ++b) {
            const float p = patch[b * T_ + tc];   // broadcast across fq lanes
            a[b * 4 + 0] += p * ww.x;
            a[b * 4 + 1] += p * ww.y;
            a[b * 4 + 2] += p * ww.z;
            a[b * 4 + 3] += p * ww.w;
        }
    }

    // ---- in-wave butterfly over the 16 in-wave t-groups (lane bits 2..5),
    // folding elements each step: 16+8+4+2 = 30 shuffles. Ends with 2
    // partials per lane at element index eg (derived from lane bits).
#define RSTEP(m, k)                                         \
    {                                                       \
        const bool hi = (tid & (m)) != 0;                   \
        _Pragma("unroll")                                   \
        for (int e = 0; e < (k); ++e) {                     \
            float v = hi ? a[e] : a[e + (k)];               \
            float r = __shfl_xor(v, (m), 64);               \
            a[e] = (hi ? a[e + (k)] : a[e]) + r;            \
        }                                                   \
    }
    RSTEP(4, 16)
    RSTEP(8, 8)
    RSTEP(16, 4)
    RSTEP(32, 2)
#undef RSTEP

    // element base this lane holds: eg and eg+1 (eg = b*4+fi layout)
    const int eg = ((tid & 4) << 2) | (tid & 8) | ((tid & 16) >> 2) | ((tid & 32) >> 4);
    const int wv = tid >> 6;
    red[wv * 128 + (eg + 0) * 4 + fq] = a[0];
    red[wv * 128 + (eg + 1) * 4 + fq] = a[1];
    __syncthreads();

    // ---- final: thread -> output (b, f); just 2 LDS reads (one per wave)
    {
        const int b   = tid >> 4;
        const int f   = tid & 15;
        const int fq2 = f >> 2;
        const int fi  = f & 3;
        const int e2  = (b * 4 + fi) * 4 + fq2;
        const float s = bi + red[e2] + red[128 + e2];
        out[((size_t)b * NLOC + loc) * F_ + f] = s;
    }
}

extern "C" void kernel_launch(void* const* d_in, const int* in_sizes, int n_in,
                              void* d_out, int out_size, void* d_ws, size_t ws_size,
                              hipStream_t stream) {
    const float* in   = (const float*)d_in[0];
    const float* wgt  = (const float*)d_in[1];
    const float* bias = (const float*)d_in[2];
    float* out = (float*)d_out;
    lc3d_kernel<<<NLOC, 128, 0, stream>>>(in, wgt, bias, out);
}